// Round 10
// baseline (2916.262 us; speedup 1.0000x reference)
//
#include <hip/hip_runtime.h>
#include <hip/hip_cooperative_groups.h>
#include <math.h>

#define SEQ    1024
#define EMBED  300
#define HIDDEN 512
#define NB     128           // worker blocks
#define NBLK   256           // total blocks (128 workers + 128 heaters)
#define TPB    256           // threads per block (4 waves)
#define UPB    (HIDDEN/NB)   // hidden units owned per worker block = 4
#define PAD_IDX 1
#define SENT   0x7FC00BADu   // NaN bit pattern: never produced by LSTM math

// g_hp layout (R9-proven): [step][producer][32 floats] -- 128 B per producer
// per step, EXCLUSIVE cache line per producer (load-bearing: R10's dense
// layout regressed 3.6x). Payload = first 16 B; only payload words carry
// sentinels (R13-proven payload-only init).
#define HSLOT  32
#define HROW   (NB * HSLOT)   // 4096 floats per step

// ---- device-global scratch. Payload re-initialized pre-grid-sync. ----
__device__ __align__(128) float g_hp[(SEQ + 1) * HROW];  // per-step h buffers
__device__ unsigned int g_done;                          // heater kill switch
__device__ float        g_sink;                          // keeps heater loops alive

__device__ __forceinline__ float sigmoidf_(float x) {
    return 1.f / (1.f + __expf(-x));
}
__device__ __forceinline__ float tanhf_(float x) {
    return 1.f - 2.f / (__expf(2.f * x) + 1.f);
}

// DPP butterfly add over 16-lane rows
#define DPP_ADD(v, ctrl)                                                      \
    (v) += __int_as_float(__builtin_amdgcn_update_dpp(                        \
        0, __float_as_int(v), (ctrl), 0xf, 0xf, true))

// 20-FMA input-projection partial: 4 independent 5-deep chains (R14 form)
__device__ __forceinline__ float ixdot(const float* er, const float4* wih) {
    float x0 = 0.f, x1 = 0.f, x2 = 0.f, x3 = 0.f;
    #pragma unroll
    for (int j = 0; j < 5; j++) {
        float4 e4 = *(const float4*)(er + 4 * j);
        x0 = fmaf(wih[j].x, e4.x, x0);
        x1 = fmaf(wih[j].y, e4.y, x1);
        x2 = fmaf(wih[j].z, e4.z, x2);
        x3 = fmaf(wih[j].w, e4.w, x3);
    }
    return (x0 + x1) + (x2 + x3);
}

// ---------------------------------------------------------------------------
// Single fused cooperative kernel, R18 = R13's W_ih-fold with a NAKED probe.
//
// R13/R14 lesson: the probe path has ~1:1 sensitivity; anything issued
// pre-poll (loads -> vmcnt drain; scans/FMA chains -> issue delay) costs
// ~100-220 ns/step. Fixes, all structural:
//  - emb rows flow through a 4-slot LDS ring (ering) filled ONLY by waves
//    2-3 (non-pollers): vmcnt is per-wave, so their prefetch can never
//    drain into the pollers' probe. Loads issue right after the barrier,
//    ds_write goes late (post-dot); slot is consumed two barriers later.
//  - ix for real-step n+1 is computed during step n's post-barrier dot
//    phase from ering, and CARRIED in a register. Pre-poll region is EMPTY
//    (cleaner than R9, which drained an xg load there every step).
//  - no xgates kernel, no g_xg, single cooperative launch (R12-proven).
// Worker exchange (probe/publish/LDS/barrier) is R9 verbatim.
// ---------------------------------------------------------------------------
__global__ __launch_bounds__(TPB, 1) void fused_kernel(
    const int* __restrict__ seq, const float* __restrict__ h0,
    const float* __restrict__ c0, const float* __restrict__ emb,
    const float* __restrict__ W_ih, const float* __restrict__ Whh,
    const float* __restrict__ b_ih, const float* __restrict__ b_hh,
    float* __restrict__ out)
{
    const int b = blockIdx.x, tid = threadIdx.x;
    const int gid = b * TPB + tid;

    // ---- phase 0: init the 16-B payload of every slot (R13-proven) ----
    for (int i = gid; i < (SEQ + 1) * NB * UPB; i += NBLK * TPB) {
        int step = i >> 9;            // NB*UPB = 512 payload words per step
        int w    = i & 511;
        int blk  = w >> 2, k = w & 3;
        float v = __uint_as_float(SENT);
        if (step == 0) v = h0[blk * UPB + k];
        g_hp[(size_t)step * HROW + blk * HSLOT + k] = v;
    }
    if (gid == 0) g_done = 0u;

    cooperative_groups::this_grid().sync();

    if (b >= NB) {
        // ---------------- pure FMA heater ----------------
        if (tid < 128) {
            float a0 = 1.0f + tid, a1 = 2.0f, a2 = 3.0f, a3 = 4.0f;
            for (;;) {
                #pragma unroll
                for (int i = 0; i < 128; i++) {
                    a0 = fmaf(a0, 1.000001f, 0.5f);
                    a1 = fmaf(a1, 0.999999f, 0.25f);
                    a2 = fmaf(a2, 1.0000005f, a0);
                    a3 = fmaf(a3, 0.9999995f, a1);
                }
                if (__hip_atomic_load(&g_done, __ATOMIC_RELAXED,
                                      __HIP_MEMORY_SCOPE_AGENT)) break;
            }
            if (a0 == 1234.5678f && a1 == a2) g_sink = a3;
        }
        return;
    }

    // ================= worker block =================
    const int u = tid >> 6;            // wave id = owned unit 0..3
    const int lane = tid & 63;
    const int g = lane >> 4, c = lane & 15;
    const int U = b * UPB + u;
    const int R = g * HIDDEN + U;      // gate row (W_ih / W_hh / biases)

    // W_hh fragment (R9): rotated traversal, 32 floats of row R
    const float* wrow = Whh + (size_t)R * HIDDEN + c * 32;
    float4 wreg[8];
    #pragma unroll
    for (int i = 0; i < 8; i++) {
        int off = (4 * i + 4 * c) & 31;
        wreg[i] = *(const float4*)(wrow + off);
    }

    // W_ih fragment: e-slice [20c, 20c+20) of row R; c==15 is zero pad
    float4 wih[5];
    #pragma unroll
    for (int j = 0; j < 5; j++) wih[j] = make_float4(0.f, 0.f, 0.f, 0.f);
    if (c < 15) {
        const float* xr = W_ih + (size_t)R * EMBED + c * 20;
        #pragma unroll
        for (int j = 0; j < 5; j++) wih[j] = *(const float4*)(xr + 4 * j);
    }
    const bool gate_lane = (c == 0);
    float bias = 0.f;
    if (gate_lane) bias = b_ih[R] + b_hh[R];

    __shared__ __align__(16) float h_lds[2][HIDDEN];
    __shared__ __align__(16) float ering[4][320];   // emb ring, 4 slots
    __shared__ int tok_lds[SEQ];

    for (int i = tid; i < SEQ; i += TPB) tok_lds[i] = seq[i];

    const bool owner = (lane == 0);
    float c_state = 0.f, h_state = 0.f;
    if (owner) {
        c_state = c0[U];
        h_state = h0[U];
    }
    __syncthreads();   // tok_lds ready

    // ---- prologue: first two real tokens into ring slots 0,1 ----
    int rt0 = 0;
    while (rt0 < SEQ && tok_lds[rt0] == PAD_IDX) rt0++;
    int rt1 = (rt0 < SEQ) ? rt0 + 1 : SEQ;
    while (rt1 < SEQ && tok_lds[rt1] == PAD_IDX) rt1++;

    if (rt0 < SEQ && tid < 75)
        *(float4*)&ering[0][4 * tid] =
            *(const float4*)(emb + (size_t)tok_lds[rt0] * EMBED + 4 * tid);
    if (rt1 < SEQ && tid >= 128 && tid < 203)
        *(float4*)&ering[1][4 * (tid - 128)] =
            *(const float4*)(emb + (size_t)tok_lds[rt1] * EMBED + 4 * (tid - 128));
    __syncthreads();

    float ixc = ixdot(&ering[0][c * 20], wih);   // ix for real step 0
    int tpre = (rt1 < SEQ) ? rt1 : SEQ;          // last prefetched real t

    int np = 0;
    bool any = false;

    for (int t = 0; t < SEQ; t++) {
        int tok = tok_lds[t];             // uniform LDS read
        if (tok == PAD_IDX) continue;     // uniform across grid
        any = true;

        // ---- pre-poll: NOTHING. Probe issues immediately (R9 probe). ----
        if (tid < NB) {
            const unsigned long long* hb_ =
                (const unsigned long long*)(g_hp + (size_t)np * HROW + tid * HSLOT);
            unsigned long long p0, p1;
            for (;;) {
                p0 = __hip_atomic_load(hb_ + 0, __ATOMIC_RELAXED,
                                       __HIP_MEMORY_SCOPE_AGENT);
                p1 = __hip_atomic_load(hb_ + 1, __ATOMIC_RELAXED,
                                       __HIP_MEMORY_SCOPE_AGENT);
                if ((unsigned)p0 != SENT && (unsigned)(p0 >> 32) != SENT &&
                    (unsigned)p1 != SENT && (unsigned)(p1 >> 32) != SENT)
                    break;
            }
            unsigned long long* dst =
                (unsigned long long*)&h_lds[np & 1][tid * UPB];
            dst[0] = p0; dst[1] = p1;
        }
        __syncthreads();   // the only barrier per step

        // ---- waves 2-3 only: ISSUE prefetch of real-token #(np+2).
        // Their vmcnt cannot touch the pollers' probe (per-wave counters).
        float4 ev = make_float4(0.f, 0.f, 0.f, 0.f);
        bool pf = false;
        const int pidx = tid - 128;
        if (tid >= 128) {
            int tn = tpre + 1;
            while (tn < SEQ && tok_lds[tn] == PAD_IDX) tn++;
            if (tn < SEQ) {
                if (pidx < 75)
                    ev = *(const float4*)(emb + (size_t)tok_lds[tn] * EMBED
                                          + 4 * pidx);
                pf = true;
                tpre = tn;
            } else {
                tpre = SEQ;
            }
        }

        // ---- dot: W_hh partials + carried ix, shared DPP reduce ----
        const float* hc = h_lds[np & 1] + c * 32;
        float4 a4 = {0.f, 0.f, 0.f, 0.f};
        #pragma unroll
        for (int i = 0; i < 8; i++) {
            int off = (4 * i + 4 * c) & 31;
            float4 h4 = *(const float4*)(hc + off);
            a4.x = fmaf(wreg[i].x, h4.x, a4.x);
            a4.y = fmaf(wreg[i].y, h4.y, a4.y);
            a4.z = fmaf(wreg[i].z, h4.z, a4.z);
            a4.w = fmaf(wreg[i].w, h4.w, a4.w);
        }
        float dotv = (a4.x + a4.y) + (a4.z + a4.w) + ixc;
        DPP_ADD(dotv, 0xB1);    // quad_perm [1,0,3,2]
        DPP_ADD(dotv, 0x4E);    // quad_perm [2,3,0,1]
        DPP_ADD(dotv, 0x141);   // row_half_mirror
        DPP_ADD(dotv, 0x140);   // row_mirror

        // ---- ix for the NEXT real step, carried in a register.
        // Slot (np+1)&3 was written >= one barrier ago.
        ixc = ixdot(&ering[(np + 1) & 3][c * 20], wih);

        // ---- late ds_write of the prefetched row (slot np+2) ----
        if (pf && pidx < 75)
            *(float4*)&ering[(np + 2) & 3][4 * pidx] = ev;

        // ---- distributed activations + owner update/publish (R9) ----
        float act = 0.f;
        if (gate_lane) {
            float z = dotv + bias;
            act = (g == 2) ? tanhf_(z) : sigmoidf_(z);
        }
        float fv = __shfl(act, 16);
        float gv = __shfl(act, 32);
        float ov = __shfl(act, 48);

        if (owner) {
            c_state = fv * c_state + act * gv;   // act == iv on lane 0
            h_state = ov * tanhf_(c_state);
            __hip_atomic_store(
                (unsigned*)(g_hp + (size_t)(np + 1) * HROW + b * HSLOT) + u,
                __float_as_uint(h_state),
                __ATOMIC_RELAXED, __HIP_MEMORY_SCOPE_AGENT);
        }
        np++;
    }

    if (owner) {
        out[U]              = any ? h_state : 0.f;  // out
        out[HIDDEN + U]     = h_state;              // h_final
        out[2 * HIDDEN + U] = c_state;              // c_final
    }
    if (b == 0 && tid == 0) {
        __hip_atomic_store(&g_done, 1u, __ATOMIC_RELAXED,
                           __HIP_MEMORY_SCOPE_AGENT);
    }
}

// ---------------------------------------------------------------------------
extern "C" void kernel_launch(void* const* d_in, const int* in_sizes, int n_in,
                              void* d_out, int out_size, void* d_ws, size_t ws_size,
                              hipStream_t stream)
{
    const int*   seq  = (const int*)  d_in[0];
    const float* h0   = (const float*)d_in[1];
    const float* c0   = (const float*)d_in[2];
    const float* emb  = (const float*)d_in[3];
    const float* W_ih = (const float*)d_in[4];
    const float* W_hh = (const float*)d_in[5];
    const float* b_ih = (const float*)d_in[6];
    const float* b_hh = (const float*)d_in[7];
    float* out = (float*)d_out;

    void* args[] = { (void*)&seq, (void*)&h0, (void*)&c0, (void*)&emb,
                     (void*)&W_ih, (void*)&W_hh, (void*)&b_ih, (void*)&b_hh,
                     (void*)&out };
    hipLaunchCooperativeKernel((const void*)fused_kernel, dim3(NBLK), dim3(TPB),
                               args, 0, stream);
}

// Round 11
// 2040.384 us; speedup vs baseline: 1.4293x; 1.4293x over previous
//
#include <hip/hip_runtime.h>
#include <hip/hip_cooperative_groups.h>
#include <math.h>

#define SEQ    1024
#define EMBED  300
#define HIDDEN 512
#define G4     2048          // 4*HIDDEN, gate order i,f,g,o
#define NB     128           // worker blocks
#define NBLK   256           // total blocks (128 workers + 128 heater/xgates)
#define TPB    256           // threads per block (4 waves)
#define UPB    (HIDDEN/NB)   // hidden units owned per worker block = 4
#define PAD_IDX 1
#define SENT   0x7FC00BADu   // NaN bit pattern: never produced by LSTM math

// g_hp layout (R9-proven): [step][producer][32 floats] -- 128 B per producer
// per step, EXCLUSIVE cache line per producer (load-bearing: R10's dense
// layout regressed 3.6x). Payload = first 16 B; only payload words init'd.
#define HSLOT  32
#define HROW   (NB * HSLOT)   // 4096 floats per step

// ---- device-global scratch ----
__device__ __align__(128) float g_xg[SEQ * G4];          // x@W_ih^T + biases
__device__ __align__(128) float g_hp[(SEQ + 1) * HROW];  // per-step h buffers
__device__ unsigned int g_done;                          // heater kill switch
__device__ float        g_sink;                          // keeps heater loops alive

__device__ __forceinline__ float sigmoidf_(float x) {
    return 1.f / (1.f + __expf(-x));
}
__device__ __forceinline__ float tanhf_(float x) {
    return 1.f - 2.f / (__expf(2.f * x) + 1.f);
}

// DPP butterfly add over 16-lane rows
#define DPP_ADD(v, ctrl)                                                      \
    (v) += __int_as_float(__builtin_amdgcn_update_dpp(                        \
        0, __float_as_int(v), (ctrl), 0xf, 0xf, true))

#define LDA(p)    __hip_atomic_load((p), __ATOMIC_RELAXED, __HIP_MEMORY_SCOPE_AGENT)
#define STA(p, v) __hip_atomic_store((p), (v), __ATOMIC_RELAXED, __HIP_MEMORY_SCOPE_AGENT)

// ---------------------------------------------------------------------------
// Single fused cooperative kernel, R19 = R12's fusion with the GEMM
// SERIALIZED behind a second grid.sync and PLAIN worker xg reads.
//
// R12 lesson: per-step agent-scope xg loads (always-MALL, ~600cy) drained
// into every probe = +219us. R13/R14/R18 lesson: per-step emb traffic is
// worse. So: xg is fully precomputed inside the dispatch, then read with
// plain L2-cacheable loads (R9/R0-identical step body).
//
// Cross-XCD safety (no bet on fence semantics):
//  - g_xg touched ONLY by agent-scope stores until sync #2 (MALL-direct,
//    no dirty L2 lines anywhere; R12-proven publish path);
//  - workers never read g_xg before sync #2;
//  - consumer keeps SENT-check + agent-scope fallback: any stale cache
//    behavior degrades to a correct MALL re-read, never to wrong data,
//    and cannot hang (MALL holds truth once heaters finish).
// ---------------------------------------------------------------------------
__global__ __launch_bounds__(TPB, 1) void fused_kernel(
    const int* __restrict__ seq, const float* __restrict__ h0,
    const float* __restrict__ c0, const float* __restrict__ emb,
    const float* __restrict__ W_ih, const float* __restrict__ Whh,
    const float* __restrict__ b_ih, const float* __restrict__ b_hh,
    float* __restrict__ out)
{
    const int b = blockIdx.x, tid = threadIdx.x;
    const int gid = b * TPB + tid;

    // ---- phase 0: g_hp payload init (R13-proven loop, plain stores) ----
    for (int i = gid; i < (SEQ + 1) * NB * UPB; i += NBLK * TPB) {
        int step = i >> 9;            // NB*UPB = 512 payload words per step
        int w    = i & 511;
        int blk  = w >> 2, k = w & 3;
        float v = __uint_as_float(SENT);
        if (step == 0) v = h0[blk * UPB + k];
        g_hp[(size_t)step * HROW + blk * HSLOT + k] = v;
    }
    // g_xg init: AGENT stores only (no L2 copies of these lines anywhere)
    for (int i = gid; i < SEQ * G4; i += NBLK * TPB)
        STA((unsigned*)&g_xg[i], SENT);
    if (gid == 0) g_done = 0u;

    cooperative_groups::this_grid().sync();   // sync #1: init visible

    if (b >= NB) {
        // ========== heater block: xgates GEMM, then sync #2, then heat =====
        const int hb = b - NB;   // 0..127
        __shared__ int tok_s[8];
        __shared__ __align__(16) float embt[8][304];

        for (int it = 0; it < 2; it++) {          // 2 items: R12-proven
            const int item   = hb + it * NB;
            const int t0     = (item >> 1) * 8;
            const int k_half = item & 1;

            if (tid < 8) tok_s[tid] = seq[t0 + tid];
            __syncthreads();
            for (int idx = tid; idx < 8 * EMBED; idx += TPB) {
                int tt = idx / EMBED;
                int e  = idx - tt * EMBED;
                embt[tt][e] = emb[(size_t)tok_s[tt] * EMBED + e];
            }
            __syncthreads();

            const int kbase = k_half * 1024 + tid;
            const float4* wr0 = (const float4*)(W_ih + (size_t)(kbase      ) * EMBED);
            const float4* wr1 = (const float4*)(W_ih + (size_t)(kbase + 256) * EMBED);
            const float4* wr2 = (const float4*)(W_ih + (size_t)(kbase + 512) * EMBED);
            const float4* wr3 = (const float4*)(W_ih + (size_t)(kbase + 768) * EMBED);

            float acc[4][8];
            #pragma unroll
            for (int kk = 0; kk < 4; kk++)
                #pragma unroll
                for (int tt = 0; tt < 8; tt++) acc[kk][tt] = 0.f;

            for (int e4 = 0; e4 < EMBED / 4; e4++) {  // 75 iters
                float4 em[8];
                #pragma unroll
                for (int tt = 0; tt < 8; tt++)
                    em[tt] = *(const float4*)&embt[tt][e4 * 4];
                float4 w[4];
                w[0] = wr0[e4]; w[1] = wr1[e4]; w[2] = wr2[e4]; w[3] = wr3[e4];
                #pragma unroll
                for (int kk = 0; kk < 4; kk++) {
                    #pragma unroll
                    for (int tt = 0; tt < 8; tt++) {
                        float a = acc[kk][tt];
                        a = fmaf(w[kk].x, em[tt].x, a);
                        a = fmaf(w[kk].y, em[tt].y, a);
                        a = fmaf(w[kk].z, em[tt].z, a);
                        a = fmaf(w[kk].w, em[tt].w, a);
                        acc[kk][tt] = a;
                    }
                }
            }
            // publish via agent stores (MALL-direct; R12-proven)
            #pragma unroll
            for (int kk = 0; kk < 4; kk++) {
                int k = kbase + kk * 256;
                float bias = b_ih[k] + b_hh[k];
                #pragma unroll
                for (int tt = 0; tt < 8; tt++) {
                    STA((unsigned*)&g_xg[(size_t)(t0 + tt) * G4 + k],
                        __float_as_uint(acc[kk][tt] + bias));
                }
            }
            __syncthreads();   // protect tok_s/embt reuse
        }

        cooperative_groups::this_grid().sync();   // sync #2: xg complete

        // ---------------- FMA heater ----------------
        if (tid < 128) {
            float a0 = 1.0f + tid, a1 = 2.0f, a2 = 3.0f, a3 = 4.0f;
            for (;;) {
                #pragma unroll
                for (int i = 0; i < 128; i++) {
                    a0 = fmaf(a0, 1.000001f, 0.5f);
                    a1 = fmaf(a1, 0.999999f, 0.25f);
                    a2 = fmaf(a2, 1.0000005f, a0);
                    a3 = fmaf(a3, 0.9999995f, a1);
                }
                if (__hip_atomic_load(&g_done, __ATOMIC_RELAXED,
                                      __HIP_MEMORY_SCOPE_AGENT)) break;
            }
            if (a0 == 1234.5678f && a1 == a2) g_sink = a3;
        }
        return;
    }

    // ========== worker block: setup overlaps the GEMM window ==========
    const int u = tid >> 6;            // wave id = owned unit 0..3
    const int lane = tid & 63;
    const int g = lane >> 4, c = lane & 15;
    const int U = b * UPB + u;
    const int R = g * HIDDEN + U;      // W_hh row

    const float* wrow = Whh + (size_t)R * HIDDEN + c * 32;
    float4 wreg[8];
    #pragma unroll
    for (int i = 0; i < 8; i++) {
        int off = (4 * i + 4 * c) & 31;   // rotated traversal (bank spread)
        wreg[i] = *(const float4*)(wrow + off);
    }

    __shared__ __align__(16) float h_lds[2][HIDDEN];
    __shared__ int tok_lds[SEQ];

    for (int i = tid; i < SEQ; i += TPB) tok_lds[i] = seq[i];

    const bool owner = (lane == 0);
    const bool gate_lane = (c == 0);     // lanes 0,16,32,48 of each wave
    float c_state = 0.f, h_state = 0.f;
    if (owner) {
        c_state = c0[U];
        h_state = h0[U];
    }
    __syncthreads();   // tok_lds ready

    cooperative_groups::this_grid().sync();   // sync #2: xg complete

    int np = 0;
    bool any = false;

    for (int t = 0; t < SEQ; t++) {
        int tok = tok_lds[t];             // uniform LDS read
        if (tok == PAD_IDX) continue;     // uniform across grid
        any = true;

        // gate-lane xg: PLAIN load (L2-cacheable) issued pre-poll; drained
        // by the probe's own vmcnt (probe MALL latency >= xg L2 latency).
        const unsigned* xp = (const unsigned*)
            &g_xg[(size_t)t * G4 + g * HIDDEN + U];
        unsigned xv = 0u;
        if (gate_lane) xv = *xp;

        // ---- 128 pollers: ONE dependent 16-B probe (R9-proven) ----
        if (tid < NB) {
            const unsigned long long* hb_ =
                (const unsigned long long*)(g_hp + (size_t)np * HROW + tid * HSLOT);
            unsigned long long p0, p1;
            for (;;) {
                p0 = __hip_atomic_load(hb_ + 0, __ATOMIC_RELAXED,
                                       __HIP_MEMORY_SCOPE_AGENT);
                p1 = __hip_atomic_load(hb_ + 1, __ATOMIC_RELAXED,
                                       __HIP_MEMORY_SCOPE_AGENT);
                if ((unsigned)p0 != SENT && (unsigned)(p0 >> 32) != SENT &&
                    (unsigned)p1 != SENT && (unsigned)(p1 >> 32) != SENT)
                    break;
            }
            unsigned long long* dst =
                (unsigned long long*)&h_lds[np & 1][tid * UPB];
            dst[0] = p0; dst[1] = p1;
        }
        __syncthreads();   // the only barrier per step

        // 32-length partial dot: W from VGPRs, h via LDS broadcasts
        const float* hc = h_lds[np & 1] + c * 32;
        float4 a4 = {0.f, 0.f, 0.f, 0.f};
        #pragma unroll
        for (int i = 0; i < 8; i++) {
            int off = (4 * i + 4 * c) & 31;
            float4 h4 = *(const float4*)(hc + off);
            a4.x = fmaf(wreg[i].x, h4.x, a4.x);
            a4.y = fmaf(wreg[i].y, h4.y, a4.y);
            a4.z = fmaf(wreg[i].z, h4.z, a4.z);
            a4.w = fmaf(wreg[i].w, h4.w, a4.w);
        }
        float dotv = (a4.x + a4.y) + (a4.z + a4.w);
        // 16-lane butterfly via DPP (xor1, xor2, half-mirror, mirror)
        DPP_ADD(dotv, 0xB1);    // quad_perm [1,0,3,2]
        DPP_ADD(dotv, 0x4E);    // quad_perm [2,3,0,1]
        DPP_ADD(dotv, 0x141);   // row_half_mirror
        DPP_ADD(dotv, 0x140);   // row_mirror

        // distributed activations; SENT fallback = correct-under-any-cache
        float act = 0.f;
        if (gate_lane) {
            if (xv == SENT) { do { xv = LDA(xp); } while (xv == SENT); }
            float z = __uint_as_float(xv) + dotv;
            act = (g == 2) ? tanhf_(z) : sigmoidf_(z);
        }
        // owner gathers ACTIVATED gate values (3 parallel shfls)
        float fv = __shfl(act, 16);
        float gv = __shfl(act, 32);
        float ov = __shfl(act, 48);

        if (owner) {
            c_state = fv * c_state + act * gv;   // act == iv on lane 0
            h_state = ov * tanhf_(c_state);
            // direct register publish into this block's exclusive line
            STA((unsigned*)(g_hp + (size_t)(np + 1) * HROW + b * HSLOT) + u,
                __float_as_uint(h_state));
        }
        np++;
    }

    if (owner) {
        out[U]              = any ? h_state : 0.f;  // out
        out[HIDDEN + U]     = h_state;              // h_final
        out[2 * HIDDEN + U] = c_state;              // c_final
    }
    if (b == 0 && tid == 0) {
        STA(&g_done, 1u);
    }
}

// ---------------------------------------------------------------------------
extern "C" void kernel_launch(void* const* d_in, const int* in_sizes, int n_in,
                              void* d_out, int out_size, void* d_ws, size_t ws_size,
                              hipStream_t stream)
{
    const int*   seq  = (const int*)  d_in[0];
    const float* h0   = (const float*)d_in[1];
    const float* c0   = (const float*)d_in[2];
    const float* emb  = (const float*)d_in[3];
    const float* W_ih = (const float*)d_in[4];
    const float* W_hh = (const float*)d_in[5];
    const float* b_ih = (const float*)d_in[6];
    const float* b_hh = (const float*)d_in[7];
    float* out = (float*)d_out;

    void* args[] = { (void*)&seq, (void*)&h0, (void*)&c0, (void*)&emb,
                     (void*)&W_ih, (void*)&W_hh, (void*)&b_ih, (void*)&b_hh,
                     (void*)&out };
    hipLaunchCooperativeKernel((const void*)fused_kernel, dim3(NBLK), dim3(TPB),
                               args, 0, stream);
}